// Round 13
// baseline (883.375 us; speedup 1.0000x reference)
//
#include <hip/hip_runtime.h>

// QuantLinear: out[T,N] = x[T,K] @ dequant(W)[K,N] + bias
// T=8192, K=4096, N=11008. Merged pre-pass: x->bf16, W->bf16 W^T [N][K].
// r13: 128x128 tiles, 4 waves (2Mx2N), 2 blocks/CU (64KB LDS x 2 buffers
// each) -- cross-block stall hiding: while one block sits at its
// barrier/vmcnt, the co-resident block's MFMA keeps the matrix pipe fed
// (m97/m112 precedent: 128^2 beats 256^2 at 2-sync-per-K-tile schedules).
// Schedule = r7/r12 proven: decoupled frag reads (1 phase ahead), 2 phases
// per K-tile, 2 sync points, vmcnt(4) ledger, st_16x32 swizzle, setprio,
// 8x8 XCD supertiles. Grid 5504 (10.75 generations, ~2% tail loss).

#define TDIM 8192
#define KDIM 4096
#define NDIM 11008

typedef __attribute__((ext_vector_type(8))) short short8;
typedef __attribute__((ext_vector_type(8))) unsigned short ushort8;
typedef __attribute__((ext_vector_type(4))) float f32x4;

__device__ __forceinline__ unsigned short f2bf(float f) {
    unsigned int u = __float_as_uint(f);
    u += 0x7FFFu + ((u >> 16) & 1u);   // round-to-nearest-even
    return (unsigned short)(u >> 16);
}

// fp4 e2m1 nibble + e8m0 exponent -> exact bf16 bits.
__device__ __forceinline__ unsigned short nib2bf(unsigned int v, int e) {
    unsigned int m3 = v & 7u;
    if (m3 == 0u) return 0;
    unsigned int s = (v & 8u) << 12;
    unsigned int E = (unsigned int)e + (m3 >> 1) - 1u;
    unsigned int man = (m3 >= 2u) ? ((m3 & 1u) << 6) : 0u;
    return (unsigned short)(s | (E << 7) | man);
}

__device__ __forceinline__ void gload_lds16(const void* g, void* l) {
    __builtin_amdgcn_global_load_lds(
        (const __attribute__((address_space(1))) void*)g,
        (__attribute__((address_space(3))) void*)l, 16, 0, 0);
}

// ---------------- merged pre-pass: convert_x (blocks <16384) + dequant_w ----------------
__global__ __launch_bounds__(256) void prepass(const float* __restrict__ x,
                                               unsigned short* __restrict__ xbf,
                                               const int* __restrict__ wp,
                                               const int* __restrict__ wse,
                                               unsigned short* __restrict__ wt) {
    __shared__ int sT[64][65];
    const int tid = threadIdx.x;
    if (blockIdx.x < 16384) {
        size_t i = ((size_t)blockIdx.x * 256 + tid) * 8;
        float4 v0 = *(const float4*)(x + i);
        float4 v1 = *(const float4*)(x + i + 4);
        ushort8 r;
        r[0] = f2bf(v0.x); r[1] = f2bf(v0.y); r[2] = f2bf(v0.z); r[3] = f2bf(v0.w);
        r[4] = f2bf(v1.x); r[5] = f2bf(v1.y); r[6] = f2bf(v1.z); r[7] = f2bf(v1.w);
        *(ushort8*)(xbf + i) = r;
        return;
    }
    const int bb = blockIdx.x - 16384;          // 0..1375
    const int n0 = (bb % 172) * 64;
    const int r0 = (bb / 172) * 64;

    #pragma unroll
    for (int i = 0; i < 16; ++i) {
        int idx = i * 256 + tid;
        int r = idx >> 6, n = idx & 63;
        sT[r][n] = wp[(size_t)(r0 + r) * NDIM + n0 + n];
    }
    __syncthreads();
    #pragma unroll
    for (int i = 0; i < 16; ++i) {
        int idx = i * 256 + tid;
        int n = idx >> 6, r = idx & 63;
        unsigned int p = (unsigned int)sT[r][n];
        int e = wse[(size_t)((r0 + r) >> 2) * NDIM + n0 + n];
        ushort8 o;
        #pragma unroll
        for (int j = 0; j < 8; ++j) o[j] = nib2bf((p >> (4 * j)) & 0xFu, e);
        *(ushort8*)(wt + (size_t)(n0 + n) * KDIM + (size_t)(r0 + r) * 8) = o;
    }
}

// --- staging: stream = one 8KB k-half (A or B); 2 gload per stream (j0: rows
//     0..63, j1: rows 64..127). Dest linear; element offsets. ---
#define STG_A(GOFF, C, HK)                                                                  \
    do {                                                                                    \
        gload_lds16(pA0 + (GOFF), ldsW + (C)*16384 + (HK)*4096);                            \
        gload_lds16(pA1 + (GOFF), ldsW + (C)*16384 + (HK)*4096 + 2048);                     \
    } while (0)

#define STG_B(GOFF, C, HK)                                                                  \
    do {                                                                                    \
        gload_lds16(pB0 + (GOFF), ldsW + (C)*16384 + 8192 + (HK)*4096);                     \
        gload_lds16(pB1 + (GOFF), ldsW + (C)*16384 + 8192 + (HK)*4096 + 2048);              \
    } while (0)

// --- frag reads (r7's verified conflict-free swizzled pattern); byte offsets ---
#define RD_A(CB, KS, DST)                                                                          \
    DST[0] = *(const short8*)(ldsC + (CB)*32768 + (KS)*8192 + (wm*4 + 0)*1024 + lbyte);            \
    DST[1] = *(const short8*)(ldsC + (CB)*32768 + (KS)*8192 + (wm*4 + 1)*1024 + lbyte);            \
    DST[2] = *(const short8*)(ldsC + (CB)*32768 + (KS)*8192 + (wm*4 + 2)*1024 + lbyte);            \
    DST[3] = *(const short8*)(ldsC + (CB)*32768 + (KS)*8192 + (wm*4 + 3)*1024 + lbyte);

#define RD_B(CB, KS, DST)                                                                          \
    DST[0] = *(const short8*)(ldsC + (CB)*32768 + 16384 + (KS)*8192 + (wn*4 + 0)*1024 + lbyte);    \
    DST[1] = *(const short8*)(ldsC + (CB)*32768 + 16384 + (KS)*8192 + (wn*4 + 1)*1024 + lbyte);    \
    DST[2] = *(const short8*)(ldsC + (CB)*32768 + 16384 + (KS)*8192 + (wn*4 + 2)*1024 + lbyte);    \
    DST[3] = *(const short8*)(ldsC + (CB)*32768 + 16384 + (KS)*8192 + (wn*4 + 3)*1024 + lbyte);

// 16 MFMA: full 4m x 4n at one k32 step
#define CLUSTER(A, B)                                                          \
    __builtin_amdgcn_s_setprio(1);                                             \
    _Pragma("unroll")                                                          \
    for (int i_ = 0; i_ < 4; ++i_) {                                           \
        _Pragma("unroll")                                                      \
        for (int n_ = 0; n_ < 4; ++n_)                                         \
            acc[i_][n_] = __builtin_amdgcn_mfma_f32_16x16x32_bf16(             \
                A[i_], B[n_], acc[i_][n_], 0, 0, 0);                           \
    }                                                                          \
    __builtin_amdgcn_s_setprio(0);

// one K-tile, 2 phases; C = tile parity (literal).
// Entry invariants: aX/bX hold tile T k0 frags (read at T-1 p1); tile T fully
// landed; outstanding = 4 loads (tile T+1 k0, issued T-1 p1).
#define BODY(T, C)                                                             \
    do {                                                                       \
        /* p0: stage T+1 k1 (A+B); read k1 frags; compute k0 */                \
        if ((T) < 63) { STG_A(96, (C)^1, 1); STG_B(96, (C)^1, 1); }            \
        RD_A((C), 1, aY)                                                       \
        RD_B((C), 1, bY)                                                       \
        CLUSTER(aX, bX)                                                        \
        /* T+1 k0 landed collectively after barrier; k0 region dead */         \
        if ((T) < 63) asm volatile("s_waitcnt vmcnt(4)" ::: "memory");         \
        __builtin_amdgcn_s_barrier();                                          \
        /* p1: stage T+2 k0 (overwrites dead k0); read NEXT k0; compute k1 */  \
        if ((T) < 62) { STG_A(128, (C), 0); STG_B(128, (C), 0); }              \
        if ((T) < 63) { RD_A((C)^1, 0, aX) RD_B((C)^1, 0, bX) }                \
        CLUSTER(aY, bY)                                                        \
        /* T+1 k1 landed collectively after barrier; k1 region dead */         \
        if ((T) < 62)       asm volatile("s_waitcnt vmcnt(4)" ::: "memory");   \
        else if ((T) == 62) asm volatile("s_waitcnt vmcnt(0)" ::: "memory");   \
        __builtin_amdgcn_s_barrier();                                          \
        pA0 += 64; pA1 += 64; pB0 += 64; pB1 += 64;                            \
    } while (0)

// ---------------- main GEMM: 128x128 tile, BK=64, 4 waves, 2 blocks/CU ----------------
__global__ __launch_bounds__(256, 2) void gemm128(const unsigned short* __restrict__ xbf,
                                                  const unsigned short* __restrict__ wt,
                                                  const float* __restrict__ bias,
                                                  float* __restrict__ out) {
    __shared__ __attribute__((aligned(16))) unsigned short lds[2][16384]; // 64 KiB
    const int tid = threadIdx.x;
    const int l = tid & 63, wid = tid >> 6;
    const int wm = wid >> 1, wn = wid & 1;   // 2 x 2 waves; wave = 64 rows x 64 cols

    // --- XCD + 8x8 supertile decode: grid 64x86 = 5504 = 8*688 ---
    int b = blockIdx.x;
    int swz = (b & 7) * 688 + (b >> 3);        // bijective
    int band = swz / 688;                       // NOTE: swz in [0,5504); band in [0,8)
    int r = swz % 688;
    int st = r >> 6; if (st > 10) st = 10;      // supertile col-group (10 full + 1 ragged)
    int ii = r - (st << 6);
    int w = (st < 10) ? 8 : 6;                  // supertile bn-width
    const int bm0 = (band * 8 + ii / w) * 128;
    const int bn0 = (st * 8 + ii % w) * 128;

    // per-thread staging decode: linear-dest 16B chunk -> (row, k) inverse swizzle
    int rs0, ks0, rs1, ks1;
    {
        int chunk = tid;                      // j=0 (rows 0..63)
        int cin = chunk & 63;
        cin ^= ((cin >> 5) & 1) << 1;
        rs0 = (chunk >> 6) * 16 + (cin >> 2);
        ks0 = (cin & 3) * 8;
        chunk = 256 + tid;                    // j=1 (rows 64..127)
        cin = chunk & 63;
        cin ^= ((cin >> 5) & 1) << 1;
        rs1 = (chunk >> 6) * 16 + (cin >> 2);
        ks1 = (cin & 3) * 8;
    }

    // incrementing staging pointers (the ONLY per-lane 64-bit address state)
    const unsigned short* pA0 = xbf + (size_t)(bm0 + rs0) * KDIM + ks0;
    const unsigned short* pA1 = xbf + (size_t)(bm0 + rs1) * KDIM + ks1;
    const unsigned short* pB0 = wt + (size_t)(bn0 + rs0) * KDIM + ks0;
    const unsigned short* pB1 = wt + (size_t)(bn0 + rs1) * KDIM + ks1;

    unsigned short* ldsW = &lds[0][0] + wid * 512;   // staging dest base (elements)
    const char* ldsC = (const char*)&lds[0][0];      // frag read base (bytes)

    // lane-constant swizzled read offset
    const int lbyte = (((l & 15) * 64 + ((l >> 4) << 4))) ^ ((l & 8) << 2);

    f32x4 acc[4][4] = {};
    short8 aX[4], aY[4], bX[4], bY[4];

    // prologue: tile 0 full + tile 1 k0 (6 streams, 12 loads)
    STG_A(0, 0, 0);   STG_B(0, 0, 0);     // t0 k0
    STG_A(32, 0, 1);  STG_B(32, 0, 1);    // t0 k1
    STG_A(64, 1, 0);  STG_B(64, 1, 0);    // t1 k0
    asm volatile("s_waitcnt vmcnt(4)" ::: "memory");   // tile 0 landed
    __builtin_amdgcn_s_barrier();
    RD_A(0, 0, aX)
    RD_B(0, 0, bX)

    for (int tt = 0; tt < 32; ++tt) {
        BODY(2 * tt, 0);
        BODY(2 * tt + 1, 1);
    }

    // epilogue: C/D layout col=lane&15, row=(lane>>4)*4+j; nontemporal stores
    const int crow = (l >> 4) * 4, ccol = l & 15;
    #pragma unroll
    for (int nf = 0; nf < 4; ++nf) {
        int col = bn0 + wn * 64 + nf * 16 + ccol;
        float bv = bias[col];
        #pragma unroll
        for (int m = 0; m < 4; ++m) {
            int row0 = bm0 + wm * 64 + m * 16 + crow;
            #pragma unroll
            for (int j2 = 0; j2 < 4; ++j2)
                __builtin_nontemporal_store(acc[m][nf][j2] + bv,
                                            &out[(size_t)(row0 + j2) * NDIM + col]);
        }
    }
}

// ---------------- fallback: fused dequant GEMM (if ws too small) ----------------
__global__ __launch_bounds__(256, 2) void gemm_fused(const float* __restrict__ x,
                                                     const int* __restrict__ wp,
                                                     const int* __restrict__ wse,
                                                     const float* __restrict__ bias,
                                                     float* __restrict__ out) {
    __shared__ __attribute__((aligned(16))) unsigned short lA[128 * 64];
    __shared__ __attribute__((aligned(16))) unsigned short lB[128 * 64];
    const int tid = threadIdx.x;
    const int l = tid & 63, wid = tid >> 6;
    const int bn0 = blockIdx.x * 128, bm0 = blockIdx.y * 128;
    const int wm = wid >> 1, wn = wid & 1;

    f32x4 acc[4][4] = {};

    for (int k0 = 0; k0 < KDIM; k0 += 64) {
        float4 av0[4], av1[4];
        unsigned int bp[4];
        int be[4];
        #pragma unroll
        for (int i = 0; i < 4; ++i) {
            int seg = i * 256 + tid;
            int row = seg >> 3, kseg = seg & 7;
            const float4* p = (const float4*)(x + (size_t)(bm0 + row) * KDIM + k0 + kseg * 8);
            av0[i] = p[0]; av1[i] = p[1];
        }
        #pragma unroll
        for (int i = 0; i < 4; ++i) {
            int idx = i * 256 + tid;
            int ln = idx & 127, lr = idx >> 7;
            bp[i] = ((const unsigned int*)wp)[(size_t)(k0 / 8 + lr) * NDIM + bn0 + ln];
            be[i] = wse[(size_t)((k0 + lr * 8) >> 5) * NDIM + bn0 + ln];
        }
        #pragma unroll
        for (int i = 0; i < 4; ++i) {
            int seg = i * 256 + tid;
            int row = seg >> 3, kseg = seg & 7;
            ushort8 r;
            r[0] = f2bf(av0[i].x); r[1] = f2bf(av0[i].y); r[2] = f2bf(av0[i].z); r[3] = f2bf(av0[i].w);
            r[4] = f2bf(av1[i].x); r[5] = f2bf(av1[i].y); r[6] = f2bf(av1[i].z); r[7] = f2bf(av1[i].w);
            *(ushort8*)&lA[row * 64 + kseg * 8] = r;
        }
        #pragma unroll
        for (int i = 0; i < 4; ++i) {
            int idx = i * 256 + tid;
            int ln = idx & 127, lr = idx >> 7;
            unsigned int p = bp[i];
            int e = be[i];
            ushort8 r;
            #pragma unroll
            for (int j = 0; j < 8; ++j) r[j] = nib2bf((p >> (4 * j)) & 0xFu, e);
            *(ushort8*)&lB[ln * 64 + lr * 8] = r;
        }
        __syncthreads();
        #pragma unroll
        for (int kc = 0; kc < 2; ++kc) {
            short8 a[4], bb[4];
            #pragma unroll
            for (int f = 0; f < 4; ++f) {
                a[f] = *(const short8*)&lA[(wm * 64 + f * 16 + (l & 15)) * 64 + kc * 32 + (l >> 4) * 8];
                bb[f] = *(const short8*)&lB[(wn * 64 + f * 16 + (l & 15)) * 64 + kc * 32 + (l >> 4) * 8];
            }
            #pragma unroll
            for (int fm = 0; fm < 4; ++fm)
                #pragma unroll
                for (int fn = 0; fn < 4; ++fn)
                    acc[fm][fn] = __builtin_amdgcn_mfma_f32_16x16x32_bf16(a[fm], bb[fn], acc[fm][fn], 0, 0, 0);
        }
        __syncthreads();
    }

    const int crow = (l >> 4) * 4, ccol = l & 15;
    #pragma unroll
    for (int fn = 0; fn < 4; ++fn) {
        int col = bn0 + wn * 64 + fn * 16 + ccol;
        float bv = bias[col];
        #pragma unroll
        for (int fm = 0; fm < 4; ++fm) {
            int row0 = bm0 + wm * 64 + fm * 16 + crow;
            #pragma unroll
            for (int j = 0; j < 4; ++j)
                out[(size_t)(row0 + j) * NDIM + col] = acc[fm][fn][j] + bv;
        }
    }
}

extern "C" void kernel_launch(void* const* d_in, const int* in_sizes, int n_in,
                              void* d_out, int out_size, void* d_ws, size_t ws_size,
                              hipStream_t stream) {
    (void)in_sizes; (void)n_in; (void)out_size;
    const float* x = (const float*)d_in[0];
    const int* wp = (const int*)d_in[1];
    const int* wse = (const int*)d_in[2];
    const float* bias = (const float*)d_in[3];
    float* out = (float*)d_out;

    const size_t xbf_bytes = (size_t)TDIM * KDIM * 2;  // 67.1 MB
    const size_t wt_bytes = (size_t)NDIM * KDIM * 2;   // 90.2 MB

    if (ws_size >= xbf_bytes + wt_bytes) {
        unsigned short* xbf = (unsigned short*)d_ws;
        unsigned short* wt = (unsigned short*)((char*)d_ws + xbf_bytes);
        prepass<<<dim3(16384 + 1376), dim3(256), 0, stream>>>(x, xbf, wp, wse, wt);
        gemm128<<<dim3((TDIM / 128) * (NDIM / 128)), dim3(256), 0, stream>>>(xbf, wt, bias, out);
    } else {
        hipLaunchKernelGGL(gemm_fused, dim3(NDIM / 128, TDIM / 128), dim3(256), 0, stream, x, wp, wse, bias, out);
    }
}

// Round 14
// 693.115 us; speedup vs baseline: 1.2745x; 1.2745x over previous
//
#include <hip/hip_runtime.h>

// QuantLinear: out[T,N] = x[T,K] @ dequant(W)[K,N] + bias
// T=8192, K=4096, N=11008. Merged pre-pass: x->bf16, W->bf16 W^T [N][K].
// r14: m201-style 8-phase discipline on the r12 skeleton. 256x(NF*64) tile,
// BK=64, 8 waves (2Mx4N). Per quadrant-phase (kc,mh): {ds_read frags
// in-phase || stage 1 granule -> barrier -> lgkmcnt(0) -> setprio -> 16 MFMA
// -> setprio(0) -> barrier}; counted vmcnt(4) ONCE per K-tile (at p4).
// Staging order/ledger byte-identical to r12. st_16x32 swizzle, XCD
// supertile map, nontemporal stores, merged 1472-block dispatch
// (1280 full + 192 half-tail).

#define TDIM 8192
#define KDIM 4096
#define NDIM 11008

typedef __attribute__((ext_vector_type(8))) short short8;
typedef __attribute__((ext_vector_type(8))) unsigned short ushort8;
typedef __attribute__((ext_vector_type(4))) float f32x4;

__device__ __forceinline__ unsigned short f2bf(float f) {
    unsigned int u = __float_as_uint(f);
    u += 0x7FFFu + ((u >> 16) & 1u);   // round-to-nearest-even
    return (unsigned short)(u >> 16);
}

// fp4 e2m1 nibble + e8m0 exponent -> exact bf16 bits.
__device__ __forceinline__ unsigned short nib2bf(unsigned int v, int e) {
    unsigned int m3 = v & 7u;
    if (m3 == 0u) return 0;
    unsigned int s = (v & 8u) << 12;
    unsigned int E = (unsigned int)e + (m3 >> 1) - 1u;
    unsigned int man = (m3 >= 2u) ? ((m3 & 1u) << 6) : 0u;
    return (unsigned short)(s | (E << 7) | man);
}

__device__ __forceinline__ void gload_lds16(const void* g, void* l) {
    __builtin_amdgcn_global_load_lds(
        (const __attribute__((address_space(1))) void*)g,
        (__attribute__((address_space(3))) void*)l, 16, 0, 0);
}

// ---------------- merged pre-pass: convert_x (blocks <16384) + dequant_w ----------------
__global__ __launch_bounds__(256) void prepass(const float* __restrict__ x,
                                               unsigned short* __restrict__ xbf,
                                               const int* __restrict__ wp,
                                               const int* __restrict__ wse,
                                               unsigned short* __restrict__ wt) {
    __shared__ int sT[64][65];
    const int tid = threadIdx.x;
    if (blockIdx.x < 16384) {
        size_t i = ((size_t)blockIdx.x * 256 + tid) * 8;
        float4 v0 = *(const float4*)(x + i);
        float4 v1 = *(const float4*)(x + i + 4);
        ushort8 r;
        r[0] = f2bf(v0.x); r[1] = f2bf(v0.y); r[2] = f2bf(v0.z); r[3] = f2bf(v0.w);
        r[4] = f2bf(v1.x); r[5] = f2bf(v1.y); r[6] = f2bf(v1.z); r[7] = f2bf(v1.w);
        *(ushort8*)(xbf + i) = r;
        return;
    }
    const int bb = blockIdx.x - 16384;          // 0..1375
    const int n0 = (bb % 172) * 64;
    const int r0 = (bb / 172) * 64;

    #pragma unroll
    for (int i = 0; i < 16; ++i) {
        int idx = i * 256 + tid;
        int r = idx >> 6, n = idx & 63;
        sT[r][n] = wp[(size_t)(r0 + r) * NDIM + n0 + n];
    }
    __syncthreads();
    #pragma unroll
    for (int i = 0; i < 16; ++i) {
        int idx = i * 256 + tid;
        int n = idx >> 6, r = idx & 63;
        unsigned int p = (unsigned int)sT[r][n];
        int e = wse[(size_t)((r0 + r) >> 2) * NDIM + n0 + n];
        ushort8 o;
        #pragma unroll
        for (int j = 0; j < 8; ++j) o[j] = nib2bf((p >> (4 * j)) & 0xFu, e);
        *(ushort8*)(wt + (size_t)(n0 + n) * KDIM + (size_t)(r0 + r) * 8) = o;
    }
}

// --- staging macros (r7 geometry). A always 2 instrs; B has NF/2 instrs. ---
#define STG_A(GOFF, C, HK)                                                                  \
    do {                                                                                    \
        gload_lds16(pA0 + (GOFF), ldsW + (C)*32768 + (HK)*8192);                            \
        gload_lds16(pA1 + (GOFF), ldsW + (C)*32768 + (HK)*8192 + 4096);                     \
    } while (0)

#define STG_B(GOFF, C, HK)                                                                  \
    do {                                                                                    \
        gload_lds16(pB0 + (GOFF), ldsW + (C)*32768 + 16384 + (HK)*8192);                    \
        if constexpr (NF == 4)                                                              \
            gload_lds16(pB1 + (GOFF), ldsW + (C)*32768 + 16384 + (HK)*8192 + 4096);         \
    } while (0)

// --- frag reads (r7's verified conflict-free pattern) ---
#define RD_A(CB, KS, MH, DST)                                                                      \
    DST[0] = *(const short8*)(ldsC + (CB)*65536 + (KS)*16384 + ((MH)*4 + 0)*1024 + aoff);          \
    DST[1] = *(const short8*)(ldsC + (CB)*65536 + (KS)*16384 + ((MH)*4 + 1)*1024 + aoff);          \
    DST[2] = *(const short8*)(ldsC + (CB)*65536 + (KS)*16384 + ((MH)*4 + 2)*1024 + aoff);          \
    DST[3] = *(const short8*)(ldsC + (CB)*65536 + (KS)*16384 + ((MH)*4 + 3)*1024 + aoff);

#define RD_B(CB, KS, DST)                                                                          \
    DST[0] = *(const short8*)(ldsC + (CB)*65536 + 32768 + (KS)*16384 + 0*1024 + boff);             \
    DST[1] = *(const short8*)(ldsC + (CB)*65536 + 32768 + (KS)*16384 + 1*1024 + boff);             \
    if constexpr (NF == 4) {                                                                       \
        DST[2] = *(const short8*)(ldsC + (CB)*65536 + 32768 + (KS)*16384 + 2*1024 + boff);         \
        DST[3] = *(const short8*)(ldsC + (CB)*65536 + 32768 + (KS)*16384 + 3*1024 + boff);         \
    }

#define CLUSTER(A, B, MH)                                                      \
    __builtin_amdgcn_s_setprio(1);                                             \
    _Pragma("unroll")                                                          \
    for (int i_ = 0; i_ < 4; ++i_) {                                           \
        _Pragma("unroll")                                                      \
        for (int n_ = 0; n_ < NF; ++n_)                                        \
            acc[(MH)*4 + i_][n_] = __builtin_amdgcn_mfma_f32_16x16x32_bf16(    \
                A[i_], B[n_], acc[(MH)*4 + i_][n_], 0, 0, 0);                  \
    }                                                                          \
    __builtin_amdgcn_s_setprio(0);

#define VWAIT_STEADY()                                                         \
    do { if constexpr (NF == 4) asm volatile("s_waitcnt vmcnt(4)" ::: "memory"); \
         else                   asm volatile("s_waitcnt vmcnt(3)" ::: "memory"); } while (0)

#define LGKM0() asm volatile("s_waitcnt lgkmcnt(0)" ::: "memory")
#define SBAR()  __builtin_amdgcn_s_barrier()

// one K-tile, 4 quadrant-phases (kc,mh); C = tile parity (literal).
// m201 phase discipline: reads+stage -> bar -> lgkm0 -> MFMA -> bar.
// Staging order identical to r12; vmcnt once per tile at p4.
#define BODY(T, C)                                                             \
    do {                                                                       \
        /* p1 (kc0,mh0); stage (T+1).A.k1 into buf C^1 (dead since T-1 p4) */  \
        RD_B((C), 0, bX)                                                       \
        RD_A((C), 0, 0, aX)                                                    \
        if ((T) < 63) STG_A(96, (C)^1, 1);                                     \
        SBAR(); LGKM0();                                                       \
        CLUSTER(aX, bX, 0)                                                     \
        SBAR();                                                                \
        /* p2 (kc0,mh1); stage (T+1).B.k1 */                                   \
        RD_A((C), 0, 1, aY)                                                    \
        if ((T) < 63) STG_B(96, (C)^1, 1);                                     \
        SBAR(); LGKM0();                                                       \
        CLUSTER(aY, bX, 1)                                                     \
        SBAR();                                                                \
        /* p3 (kc1,mh0); buf C k0 dead after p2's exit bar; stage (T+2).A.k0 */\
        RD_B((C), 1, bY)                                                       \
        RD_A((C), 1, 0, aX)                                                    \
        if ((T) < 62) STG_A(128, (C), 0);                                      \
        SBAR(); LGKM0();                                                       \
        CLUSTER(aX, bY, 0)                                                     \
        SBAR();                                                                \
        /* p4 (kc1,mh1); stage (T+2).B.k0; counted vmcnt once per tile:       */\
        /* leaves only (T+2).k0 granules outstanding -> T+1 fully landed      */\
        RD_A((C), 1, 1, aY)                                                    \
        if ((T) < 62) { STG_B(128, (C), 0); VWAIT_STEADY(); }                  \
        else if ((T) == 62) asm volatile("s_waitcnt vmcnt(0)" ::: "memory");   \
        SBAR(); LGKM0();                                                       \
        CLUSTER(aY, bY, 1)                                                     \
        SBAR();                                                                \
        pA0 += 64; pA1 += 64; pB0 += 64; pB1 += 64;                            \
    } while (0)

// ---------------- GEMM body: 256x(NF*64) tile, BK=64, 8 waves ----------------
// NF=4: full 256x256 tiles, b in [0,1280). NF=2: 256x128 halves, b in [0,192).
template<int NF>
__device__ __forceinline__ void gemm_body(int b, unsigned short* ldsBase,
                                          const unsigned short* __restrict__ xbf,
                                          const unsigned short* __restrict__ wt,
                                          const float* __restrict__ bias,
                                          float* __restrict__ out) {
    const int tid = threadIdx.x;
    const int l = tid & 63, wid = tid >> 6;
    const int wm = wid >> 2, wn = wid & 3;   // 2 x 4 waves; wave = 128 rows x NF*16 cols

    // --- block -> tile decode (XCD swizzle per segment + supertile map) ---
    int swz, half = 0;
    if constexpr (NF == 4) {
        swz = (b & 7) * 160 + (b >> 3);        // bijective: 1280 = 8*160
    } else {
        int js = (b & 7) * 24 + (b >> 3);      // bijective: 192 = 8*24
        swz = 1280 + (js >> 1);
        half = js & 1;
    }
    int band = swz / 344;
    int r = swz % 344;
    int st = r >> 5; if (st > 10) st = 10;
    int ii = r - (st << 5);
    int w = (st < 10) ? 4 : 3;
    const int bm0 = (band * 8 + ii / w) * 256;
    const int bn0 = (st * 4 + ii % w) * 256 + half * 128;

    // per-thread staging decode: linear-dest 16B chunk -> (row, k) inverse swizzle
    int rs0, ks0, rs1, ks1;
    {
        int chunk = wid * 64 + l;             // j=0 (rows 0..127)
        int cin = chunk & 63;
        cin ^= ((cin >> 5) & 1) << 1;
        rs0 = (chunk >> 6) * 16 + (cin >> 2);
        ks0 = (cin & 3) * 8;
        chunk = 512 + wid * 64 + l;           // j=1 (rows 128..255)
        cin = chunk & 63;
        cin ^= ((cin >> 5) & 1) << 1;
        rs1 = (chunk >> 6) * 16 + (cin >> 2);
        ks1 = (cin & 3) * 8;
    }

    // incrementing staging pointers (the ONLY per-lane 64-bit address state)
    const unsigned short* pA0 = xbf + (size_t)(bm0 + rs0) * KDIM + ks0;
    const unsigned short* pA1 = xbf + (size_t)(bm0 + rs1) * KDIM + ks1;
    const unsigned short* pB0 = wt + (size_t)(bn0 + rs0) * KDIM + ks0;
    const unsigned short* pB1 = wt + (size_t)(bn0 + rs1) * KDIM + ks1;   // unused NF=2

    unsigned short* ldsW = ldsBase + wid * 512;       // staging dest base (elements)
    const char* ldsC = (const char*)ldsBase;          // frag read base (bytes)

    // lane-constant swizzled read offsets
    const int lbyte = (((l & 15) * 64 + ((l >> 4) << 4))) ^ ((l & 8) << 2);
    const int aoff = wm * 8192 + lbyte;
    const int boff = wn * (NF * 1024) + lbyte;

    f32x4 acc[8][4] = {};
    short8 aX[4], aY[4], bX[4], bY[4];

    // prologue: tile 0 full + tile 1 k0. vmcnt leaves t1.k0 outstanding ->
    // t0 fully landed (incl. k1, read at T=0 p3).
    STG_A(0, 0, 0);   STG_B(0, 0, 0);     // t0 k0
    STG_A(32, 0, 1);  STG_B(32, 0, 1);    // t0 k1
    STG_A(64, 1, 0);  STG_B(64, 1, 0);    // t1 k0
    VWAIT_STEADY();
    SBAR();

    for (int tt = 0; tt < 32; ++tt) {
        BODY(2 * tt, 0);
        BODY(2 * tt + 1, 1);
    }

    // epilogue: C/D layout col=lane&15, row=(lane>>4)*4+j; nontemporal stores
    const int crow = (l >> 4) * 4, ccol = l & 15;
    #pragma unroll
    for (int nf = 0; nf < NF; ++nf) {
        int col = bn0 + wn * (NF * 16) + nf * 16 + ccol;
        float bv = bias[col];
        #pragma unroll
        for (int m = 0; m < 8; ++m) {
            int row0 = bm0 + wm * 128 + m * 16 + crow;
            #pragma unroll
            for (int j2 = 0; j2 < 4; ++j2)
                __builtin_nontemporal_store(acc[m][nf][j2] + bv,
                                            &out[(size_t)(row0 + j2) * NDIM + col]);
        }
    }
}

// ---------------- merged GEMM dispatch: 1280 full + 192 half blocks ----------------
__global__ __launch_bounds__(512, 1) void gemm_all(const unsigned short* __restrict__ xbf,
                                                   const unsigned short* __restrict__ wt,
                                                   const float* __restrict__ bias,
                                                   float* __restrict__ out) {
    __shared__ __attribute__((aligned(16))) unsigned short lds[2][2][16384]; // 128 KiB
    int b = blockIdx.x;
    if (b < 1280) gemm_body<4>(b, &lds[0][0][0], xbf, wt, bias, out);
    else          gemm_body<2>(b - 1280, &lds[0][0][0], xbf, wt, bias, out);
}

// ---------------- fallback: fused dequant GEMM (if ws too small) ----------------
__global__ __launch_bounds__(256, 2) void gemm_fused(const float* __restrict__ x,
                                                     const int* __restrict__ wp,
                                                     const int* __restrict__ wse,
                                                     const float* __restrict__ bias,
                                                     float* __restrict__ out) {
    __shared__ __attribute__((aligned(16))) unsigned short lA[128 * 64];
    __shared__ __attribute__((aligned(16))) unsigned short lB[128 * 64];
    const int tid = threadIdx.x;
    const int l = tid & 63, wid = tid >> 6;
    const int bn0 = blockIdx.x * 128, bm0 = blockIdx.y * 128;
    const int wm = wid >> 1, wn = wid & 1;

    f32x4 acc[4][4] = {};

    for (int k0 = 0; k0 < KDIM; k0 += 64) {
        float4 av0[4], av1[4];
        unsigned int bp[4];
        int be[4];
        #pragma unroll
        for (int i = 0; i < 4; ++i) {
            int seg = i * 256 + tid;
            int row = seg >> 3, kseg = seg & 7;
            const float4* p = (const float4*)(x + (size_t)(bm0 + row) * KDIM + k0 + kseg * 8);
            av0[i] = p[0]; av1[i] = p[1];
        }
        #pragma unroll
        for (int i = 0; i < 4; ++i) {
            int idx = i * 256 + tid;
            int ln = idx & 127, lr = idx >> 7;
            bp[i] = ((const unsigned int*)wp)[(size_t)(k0 / 8 + lr) * NDIM + bn0 + ln];
            be[i] = wse[(size_t)((k0 + lr * 8) >> 5) * NDIM + bn0 + ln];
        }
        #pragma unroll
        for (int i = 0; i < 4; ++i) {
            int seg = i * 256 + tid;
            int row = seg >> 3, kseg = seg & 7;
            ushort8 r;
            r[0] = f2bf(av0[i].x); r[1] = f2bf(av0[i].y); r[2] = f2bf(av0[i].z); r[3] = f2bf(av0[i].w);
            r[4] = f2bf(av1[i].x); r[5] = f2bf(av1[i].y); r[6] = f2bf(av1[i].z); r[7] = f2bf(av1[i].w);
            *(ushort8*)&lA[row * 64 + kseg * 8] = r;
        }
        #pragma unroll
        for (int i = 0; i < 4; ++i) {
            int idx = i * 256 + tid;
            int ln = idx & 127, lr = idx >> 7;
            unsigned int p = bp[i];
            int e = be[i];
            ushort8 r;
            #pragma unroll
            for (int j = 0; j < 8; ++j) r[j] = nib2bf((p >> (4 * j)) & 0xFu, e);
            *(ushort8*)&lB[ln * 64 + lr * 8] = r;
        }
        __syncthreads();
        #pragma unroll
        for (int kc = 0; kc < 2; ++kc) {
            short8 a[4], bb[4];
            #pragma unroll
            for (int f = 0; f < 4; ++f) {
                a[f] = *(const short8*)&lA[(wm * 64 + f * 16 + (l & 15)) * 64 + kc * 32 + (l >> 4) * 8];
                bb[f] = *(const short8*)&lB[(wn * 64 + f * 16 + (l & 15)) * 64 + kc * 32 + (l >> 4) * 8];
            }
            #pragma unroll
            for (int fm = 0; fm < 4; ++fm)
                #pragma unroll
                for (int fn = 0; fn < 4; ++fn)
                    acc[fm][fn] = __builtin_amdgcn_mfma_f32_16x16x32_bf16(a[fm], bb[fn], acc[fm][fn], 0, 0, 0);
        }
        __syncthreads();
    }

    const int crow = (l >> 4) * 4, ccol = l & 15;
    #pragma unroll
    for (int fn = 0; fn < 4; ++fn) {
        int col = bn0 + wn * 64 + fn * 16 + ccol;
        float bv = bias[col];
        #pragma unroll
        for (int fm = 0; fm < 4; ++fm) {
            int row0 = bm0 + wm * 64 + fm * 16 + crow;
            #pragma unroll
            for (int j = 0; j < 4; ++j)
                out[(size_t)(row0 + j) * NDIM + col] = acc[fm][fn][j] + bv;
        }
    }
}

extern "C" void kernel_launch(void* const* d_in, const int* in_sizes, int n_in,
                              void* d_out, int out_size, void* d_ws, size_t ws_size,
                              hipStream_t stream) {
    (void)in_sizes; (void)n_in; (void)out_size;
    const float* x = (const float*)d_in[0];
    const int* wp = (const int*)d_in[1];
    const int* wse = (const int*)d_in[2];
    const float* bias = (const float*)d_in[3];
    float* out = (float*)d_out;

    const size_t xbf_bytes = (size_t)TDIM * KDIM * 2;  // 67.1 MB
    const size_t wt_bytes = (size_t)NDIM * KDIM * 2;   // 90.2 MB

    if (ws_size >= xbf_bytes + wt_bytes) {
        unsigned short* xbf = (unsigned short*)d_ws;
        unsigned short* wt = (unsigned short*)((char*)d_ws + xbf_bytes);
        prepass<<<dim3(16384 + 1376), dim3(256), 0, stream>>>(x, xbf, wp, wse, wt);
        gemm_all<<<dim3(1472), dim3(512), 0, stream>>>(xbf, wt, bias, out);
    } else {
        hipLaunchKernelGGL(gemm_fused, dim3(NDIM / 128, TDIM / 128), dim3(256), 0, stream, x, wp, wse, bias, out);
    }
}

// Round 15
// 667.915 us; speedup vs baseline: 1.3226x; 1.0377x over previous
//
#include <hip/hip_runtime.h>

// QuantLinear: out[T,N] = x[T,K] @ dequant(W)[K,N] + bias
// T=8192, K=4096, N=11008. Merged pre-pass: x->bf16, W->bf16 W^T [N][K].
// Main GEMM (r12 = empirical best: 0 conflicts, 56.2% MfmaUtil, 620us):
// 256x(NF*64) tile, BK=64, 8 waves, 16x16x32 MFMA, decoupled 4-phase K-tile
// (MFMA consumes frags ds_read 1 phase earlier), 2 sync points/K-tile,
// st_16x32 swizzle, counted vmcnt, setprio, XCD supertile map, nontemporal
// stores. SINGLE merged GEMM dispatch (1472 blocks): 0..1279 full 256x256
// (5 CU-rounds), 1280..1471 half 256x128 tail (backfills stragglers).
// Measured-worse alternatives: 32x32 MFMA (r8/r9/r11), 128^2 tiles (r13),
// m201 8-phase in-phase reads (r14).

#define TDIM 8192
#define KDIM 4096
#define NDIM 11008

typedef __attribute__((ext_vector_type(8))) short short8;
typedef __attribute__((ext_vector_type(8))) unsigned short ushort8;
typedef __attribute__((ext_vector_type(4))) float f32x4;

__device__ __forceinline__ unsigned short f2bf(float f) {
    unsigned int u = __float_as_uint(f);
    u += 0x7FFFu + ((u >> 16) & 1u);   // round-to-nearest-even
    return (unsigned short)(u >> 16);
}

// fp4 e2m1 nibble + e8m0 exponent -> exact bf16 bits.
__device__ __forceinline__ unsigned short nib2bf(unsigned int v, int e) {
    unsigned int m3 = v & 7u;
    if (m3 == 0u) return 0;
    unsigned int s = (v & 8u) << 12;
    unsigned int E = (unsigned int)e + (m3 >> 1) - 1u;
    unsigned int man = (m3 >= 2u) ? ((m3 & 1u) << 6) : 0u;
    return (unsigned short)(s | (E << 7) | man);
}

__device__ __forceinline__ void gload_lds16(const void* g, void* l) {
    __builtin_amdgcn_global_load_lds(
        (const __attribute__((address_space(1))) void*)g,
        (__attribute__((address_space(3))) void*)l, 16, 0, 0);
}

// ---------------- merged pre-pass: convert_x (blocks <16384) + dequant_w ----------------
__global__ __launch_bounds__(256) void prepass(const float* __restrict__ x,
                                               unsigned short* __restrict__ xbf,
                                               const int* __restrict__ wp,
                                               const int* __restrict__ wse,
                                               unsigned short* __restrict__ wt) {
    __shared__ int sT[64][65];
    const int tid = threadIdx.x;
    if (blockIdx.x < 16384) {
        size_t i = ((size_t)blockIdx.x * 256 + tid) * 8;
        float4 v0 = *(const float4*)(x + i);
        float4 v1 = *(const float4*)(x + i + 4);
        ushort8 r;
        r[0] = f2bf(v0.x); r[1] = f2bf(v0.y); r[2] = f2bf(v0.z); r[3] = f2bf(v0.w);
        r[4] = f2bf(v1.x); r[5] = f2bf(v1.y); r[6] = f2bf(v1.z); r[7] = f2bf(v1.w);
        *(ushort8*)(xbf + i) = r;
        return;
    }
    const int bb = blockIdx.x - 16384;          // 0..1375
    const int n0 = (bb % 172) * 64;
    const int r0 = (bb / 172) * 64;

    #pragma unroll
    for (int i = 0; i < 16; ++i) {
        int idx = i * 256 + tid;
        int r = idx >> 6, n = idx & 63;
        sT[r][n] = wp[(size_t)(r0 + r) * NDIM + n0 + n];
    }
    __syncthreads();
    #pragma unroll
    for (int i = 0; i < 16; ++i) {
        int idx = i * 256 + tid;
        int n = idx >> 6, r = idx & 63;
        unsigned int p = (unsigned int)sT[r][n];
        int e = wse[(size_t)((r0 + r) >> 2) * NDIM + n0 + n];
        ushort8 o;
        #pragma unroll
        for (int j = 0; j < 8; ++j) o[j] = nib2bf((p >> (4 * j)) & 0xFu, e);
        *(ushort8*)(wt + (size_t)(n0 + n) * KDIM + (size_t)(r0 + r) * 8) = o;
    }
}

// --- staging macros (r7 geometry). A always 2 instrs; B has NF/2 instrs. ---
#define STG_A(GOFF, C, HK)                                                                  \
    do {                                                                                    \
        gload_lds16(pA0 + (GOFF), ldsW + (C)*32768 + (HK)*8192);                            \
        gload_lds16(pA1 + (GOFF), ldsW + (C)*32768 + (HK)*8192 + 4096);                     \
    } while (0)

#define STG_B(GOFF, C, HK)                                                                  \
    do {                                                                                    \
        gload_lds16(pB0 + (GOFF), ldsW + (C)*32768 + 16384 + (HK)*8192);                    \
        if constexpr (NF == 4)                                                              \
            gload_lds16(pB1 + (GOFF), ldsW + (C)*32768 + 16384 + (HK)*8192 + 4096);         \
    } while (0)

// --- frag reads (r7's verified conflict-free pattern) ---
#define RD_A(CB, KS, MH, DST)                                                                      \
    DST[0] = *(const short8*)(ldsC + (CB)*65536 + (KS)*16384 + ((MH)*4 + 0)*1024 + aoff);          \
    DST[1] = *(const short8*)(ldsC + (CB)*65536 + (KS)*16384 + ((MH)*4 + 1)*1024 + aoff);          \
    DST[2] = *(const short8*)(ldsC + (CB)*65536 + (KS)*16384 + ((MH)*4 + 2)*1024 + aoff);          \
    DST[3] = *(const short8*)(ldsC + (CB)*65536 + (KS)*16384 + ((MH)*4 + 3)*1024 + aoff);

#define RD_B(CB, KS, DST)                                                                          \
    DST[0] = *(const short8*)(ldsC + (CB)*65536 + 32768 + (KS)*16384 + 0*1024 + boff);             \
    DST[1] = *(const short8*)(ldsC + (CB)*65536 + 32768 + (KS)*16384 + 1*1024 + boff);             \
    if constexpr (NF == 4) {                                                                       \
        DST[2] = *(const short8*)(ldsC + (CB)*65536 + 32768 + (KS)*16384 + 2*1024 + boff);         \
        DST[3] = *(const short8*)(ldsC + (CB)*65536 + 32768 + (KS)*16384 + 3*1024 + boff);         \
    }

#define CLUSTER(A, B, MH)                                                      \
    __builtin_amdgcn_s_setprio(1);                                             \
    _Pragma("unroll")                                                          \
    for (int i_ = 0; i_ < 4; ++i_) {                                           \
        _Pragma("unroll")                                                      \
        for (int n_ = 0; n_ < NF; ++n_)                                        \
            acc[(MH)*4 + i_][n_] = __builtin_amdgcn_mfma_f32_16x16x32_bf16(    \
                A[i_], B[n_], acc[(MH)*4 + i_][n_], 0, 0, 0);                  \
    }                                                                          \
    __builtin_amdgcn_s_setprio(0);

#define VWAIT_STEADY()                                                         \
    do { if constexpr (NF == 4) asm volatile("s_waitcnt vmcnt(4)" ::: "memory"); \
         else                   asm volatile("s_waitcnt vmcnt(3)" ::: "memory"); } while (0)

// one K-tile, 4 phases; C = tile parity (literal). r7 vmcnt ledger.
#define BODY(T, C)                                                             \
    do {                                                                       \
        /* p0: stage tile T+1 A.k1; read k0/m1; compute k0/m0 */               \
        if ((T) < 63) STG_A(96, (C)^1, 1);                                     \
        RD_A((C), 0, 1, aY)                                                    \
        CLUSTER(aX, bX, 0)                                                     \
        /* p1: stage tile T+1 B.k1; read k1 B + k1/m0; compute k0/m1 */        \
        if ((T) < 63) STG_B(96, (C)^1, 1);                                     \
        RD_B((C), 1, bY)                                                       \
        RD_A((C), 1, 0, aX)                                                    \
        CLUSTER(aY, bX, 1)                                                     \
        /* collective: tile T+1 k0 landed after barrier; k0 region dead */     \
        if ((T) < 63) VWAIT_STEADY();                                          \
        __builtin_amdgcn_s_barrier();                                          \
        /* p2: stage tile T+2 A.k0 (overwrites dead k0); compute k1/m0 */      \
        if ((T) < 62) STG_A(128, (C), 0);                                      \
        RD_A((C), 1, 1, aY)                                                    \
        CLUSTER(aX, bY, 0)                                                     \
        /* p3: stage tile T+2 B.k0; read NEXT tile's k0 frags */               \
        if ((T) < 62) STG_B(128, (C), 0);                                      \
        if ((T) < 63) { RD_B((C)^1, 0, bX) RD_A((C)^1, 0, 0, aX) }             \
        CLUSTER(aY, bY, 1)                                                     \
        if ((T) < 62)       VWAIT_STEADY();                                    \
        else if ((T) == 62) asm volatile("s_waitcnt vmcnt(0)" ::: "memory");   \
        __builtin_amdgcn_s_barrier();                                          \
        pA0 += 64; pA1 += 64; pB0 += 64; pB1 += 64;                            \
    } while (0)

// ---------------- GEMM body: 256x(NF*64) tile, BK=64, 8 waves ----------------
// NF=4: full 256x256 tiles, b in [0,1280). NF=2: 256x128 halves, b in [0,192).
template<int NF>
__device__ __forceinline__ void gemm_body(int b, unsigned short* ldsBase,
                                          const unsigned short* __restrict__ xbf,
                                          const unsigned short* __restrict__ wt,
                                          const float* __restrict__ bias,
                                          float* __restrict__ out) {
    const int tid = threadIdx.x;
    const int l = tid & 63, wid = tid >> 6;
    const int wm = wid >> 2, wn = wid & 3;   // 2 x 4 waves; wave = 128 rows x NF*16 cols

    // --- block -> tile decode (XCD swizzle per segment + supertile map) ---
    int swz, half = 0;
    if constexpr (NF == 4) {
        swz = (b & 7) * 160 + (b >> 3);        // bijective: 1280 = 8*160
    } else {
        int js = (b & 7) * 24 + (b >> 3);      // bijective: 192 = 8*24
        swz = 1280 + (js >> 1);
        half = js & 1;
    }
    int band = swz / 344;
    int r = swz % 344;
    int st = r >> 5; if (st > 10) st = 10;
    int ii = r - (st << 5);
    int w = (st < 10) ? 4 : 3;
    const int bm0 = (band * 8 + ii / w) * 256;
    const int bn0 = (st * 4 + ii % w) * 256 + half * 128;

    // per-thread staging decode: linear-dest 16B chunk -> (row, k) inverse swizzle
    int rs0, ks0, rs1, ks1;
    {
        int chunk = wid * 64 + l;             // j=0 (rows 0..127)
        int cin = chunk & 63;
        cin ^= ((cin >> 5) & 1) << 1;
        rs0 = (chunk >> 6) * 16 + (cin >> 2);
        ks0 = (cin & 3) * 8;
        chunk = 512 + wid * 64 + l;           // j=1 (rows 128..255)
        cin = chunk & 63;
        cin ^= ((cin >> 5) & 1) << 1;
        rs1 = (chunk >> 6) * 16 + (cin >> 2);
        ks1 = (cin & 3) * 8;
    }

    // incrementing staging pointers (the ONLY per-lane 64-bit address state)
    const unsigned short* pA0 = xbf + (size_t)(bm0 + rs0) * KDIM + ks0;
    const unsigned short* pA1 = xbf + (size_t)(bm0 + rs1) * KDIM + ks1;
    const unsigned short* pB0 = wt + (size_t)(bn0 + rs0) * KDIM + ks0;
    const unsigned short* pB1 = wt + (size_t)(bn0 + rs1) * KDIM + ks1;   // unused NF=2

    unsigned short* ldsW = ldsBase + wid * 512;       // staging dest base (elements)
    const char* ldsC = (const char*)ldsBase;          // frag read base (bytes)

    // lane-constant swizzled read offsets
    const int lbyte = (((l & 15) * 64 + ((l >> 4) << 4))) ^ ((l & 8) << 2);
    const int aoff = wm * 8192 + lbyte;
    const int boff = wn * (NF * 1024) + lbyte;

    f32x4 acc[8][4] = {};
    short8 aX[4], aY[4], bX[4], bY[4];

    // prologue: tile 0 full + tile 1 k0
    STG_A(0, 0, 0);   STG_B(0, 0, 0);     // t0 k0
    STG_A(32, 0, 1);  STG_B(32, 0, 1);    // t0 k1
    STG_A(64, 1, 0);  STG_B(64, 1, 0);    // t1 k0
    VWAIT_STEADY();
    __builtin_amdgcn_s_barrier();
    RD_B(0, 0, bX)
    RD_A(0, 0, 0, aX)

    for (int tt = 0; tt < 32; ++tt) {
        BODY(2 * tt, 0);
        BODY(2 * tt + 1, 1);
    }

    // epilogue: C/D layout col=lane&15, row=(lane>>4)*4+j; nontemporal stores
    const int crow = (l >> 4) * 4, ccol = l & 15;
    #pragma unroll
    for (int nf = 0; nf < NF; ++nf) {
        int col = bn0 + wn * (NF * 16) + nf * 16 + ccol;
        float bv = bias[col];
        #pragma unroll
        for (int m = 0; m < 8; ++m) {
            int row0 = bm0 + wm * 128 + m * 16 + crow;
            #pragma unroll
            for (int j2 = 0; j2 < 4; ++j2)
                __builtin_nontemporal_store(acc[m][nf][j2] + bv,
                                            &out[(size_t)(row0 + j2) * NDIM + col]);
        }
    }
}

// ---------------- merged GEMM dispatch: 1280 full + 192 half blocks ----------------
__global__ __launch_bounds__(512, 1) void gemm_all(const unsigned short* __restrict__ xbf,
                                                   const unsigned short* __restrict__ wt,
                                                   const float* __restrict__ bias,
                                                   float* __restrict__ out) {
    __shared__ __attribute__((aligned(16))) unsigned short lds[2][2][16384]; // 128 KiB
    int b = blockIdx.x;
    if (b < 1280) gemm_body<4>(b, &lds[0][0][0], xbf, wt, bias, out);
    else          gemm_body<2>(b - 1280, &lds[0][0][0], xbf, wt, bias, out);
}

// ---------------- fallback: fused dequant GEMM (if ws too small) ----------------
__global__ __launch_bounds__(256, 2) void gemm_fused(const float* __restrict__ x,
                                                     const int* __restrict__ wp,
                                                     const int* __restrict__ wse,
                                                     const float* __restrict__ bias,
                                                     float* __restrict__ out) {
    __shared__ __attribute__((aligned(16))) unsigned short lA[128 * 64];
    __shared__ __attribute__((aligned(16))) unsigned short lB[128 * 64];
    const int tid = threadIdx.x;
    const int l = tid & 63, wid = tid >> 6;
    const int bn0 = blockIdx.x * 128, bm0 = blockIdx.y * 128;
    const int wm = wid >> 1, wn = wid & 1;

    f32x4 acc[4][4] = {};

    for (int k0 = 0; k0 < KDIM; k0 += 64) {
        float4 av0[4], av1[4];
        unsigned int bp[4];
        int be[4];
        #pragma unroll
        for (int i = 0; i < 4; ++i) {
            int seg = i * 256 + tid;
            int row = seg >> 3, kseg = seg & 7;
            const float4* p = (const float4*)(x + (size_t)(bm0 + row) * KDIM + k0 + kseg * 8);
            av0[i] = p[0]; av1[i] = p[1];
        }
        #pragma unroll
        for (int i = 0; i < 4; ++i) {
            int idx = i * 256 + tid;
            int ln = idx & 127, lr = idx >> 7;
            bp[i] = ((const unsigned int*)wp)[(size_t)(k0 / 8 + lr) * NDIM + bn0 + ln];
            be[i] = wse[(size_t)((k0 + lr * 8) >> 5) * NDIM + bn0 + ln];
        }
        #pragma unroll
        for (int i = 0; i < 4; ++i) {
            int seg = i * 256 + tid;
            int row = seg >> 3, kseg = seg & 7;
            ushort8 r;
            r[0] = f2bf(av0[i].x); r[1] = f2bf(av0[i].y); r[2] = f2bf(av0[i].z); r[3] = f2bf(av0[i].w);
            r[4] = f2bf(av1[i].x); r[5] = f2bf(av1[i].y); r[6] = f2bf(av1[i].z); r[7] = f2bf(av1[i].w);
            *(ushort8*)&lA[row * 64 + kseg * 8] = r;
        }
        #pragma unroll
        for (int i = 0; i < 4; ++i) {
            int idx = i * 256 + tid;
            int ln = idx & 127, lr = idx >> 7;
            unsigned int p = bp[i];
            int e = be[i];
            ushort8 r;
            #pragma unroll
            for (int j = 0; j < 8; ++j) r[j] = nib2bf((p >> (4 * j)) & 0xFu, e);
            *(ushort8*)&lB[ln * 64 + lr * 8] = r;
        }
        __syncthreads();
        #pragma unroll
        for (int kc = 0; kc < 2; ++kc) {
            short8 a[4], bb[4];
            #pragma unroll
            for (int f = 0; f < 4; ++f) {
                a[f] = *(const short8*)&lA[(wm * 64 + f * 16 + (l & 15)) * 64 + kc * 32 + (l >> 4) * 8];
                bb[f] = *(const short8*)&lB[(wn * 64 + f * 16 + (l & 15)) * 64 + kc * 32 + (l >> 4) * 8];
            }
            #pragma unroll
            for (int fm = 0; fm < 4; ++fm)
                #pragma unroll
                for (int fn = 0; fn < 4; ++fn)
                    acc[fm][fn] = __builtin_amdgcn_mfma_f32_16x16x32_bf16(a[fm], bb[fn], acc[fm][fn], 0, 0, 0);
        }
        __syncthreads();
    }

    const int crow = (l >> 4) * 4, ccol = l & 15;
    #pragma unroll
    for (int fn = 0; fn < 4; ++fn) {
        int col = bn0 + wn * 64 + fn * 16 + ccol;
        float bv = bias[col];
        #pragma unroll
        for (int fm = 0; fm < 4; ++fm) {
            int row0 = bm0 + wm * 64 + fm * 16 + crow;
            #pragma unroll
            for (int j = 0; j < 4; ++j)
                out[(size_t)(row0 + j) * NDIM + col] = acc[fm][fn][j] + bv;
        }
    }
}

extern "C" void kernel_launch(void* const* d_in, const int* in_sizes, int n_in,
                              void* d_out, int out_size, void* d_ws, size_t ws_size,
                              hipStream_t stream) {
    (void)in_sizes; (void)n_in; (void)out_size;
    const float* x = (const float*)d_in[0];
    const int* wp = (const int*)d_in[1];
    const int* wse = (const int*)d_in[2];
    const float* bias = (const float*)d_in[3];
    float* out = (float*)d_out;

    const size_t xbf_bytes = (size_t)TDIM * KDIM * 2;  // 67.1 MB
    const size_t wt_bytes = (size_t)NDIM * KDIM * 2;   // 90.2 MB

    if (ws_size >= xbf_bytes + wt_bytes) {
        unsigned short* xbf = (unsigned short*)d_ws;
        unsigned short* wt = (unsigned short*)((char*)d_ws + xbf_bytes);
        prepass<<<dim3(16384 + 1376), dim3(256), 0, stream>>>(x, xbf, wp, wse, wt);
        gemm_all<<<dim3(1472), dim3(512), 0, stream>>>(xbf, wt, bias, out);
    } else {
        hipLaunchKernelGGL(gemm_fused, dim3(NDIM / 128, TDIM / 128), dim3(256), 0, stream, x, wp, wse, bias, out);
    }
}